// Round 20
// baseline (566.509 us; speedup 1.0000x reference)
//
#include <hip/hip_runtime.h>
#include <hip/hip_bf16.h>

static constexpr int EDIM = 128;   // embedding size
static constexpr int FIN  = 256;   // input features
static constexpr int NSB  = 64;    // hist/scatter blocks (slice per block)
static constexpr int RB   = 128;   // rows per bin (bin = row>>7)

typedef __attribute__((ext_vector_type(8))) short bf16x8;
typedef __attribute__((ext_vector_type(4))) float f32x4;

__device__ inline short f2b(float f) {
    __hip_bfloat16 h = __float2bfloat16(f);
    return *reinterpret_cast<short*>(&h);
}

// ---------------------------------------------------------------------------
// Prep: fragment-major bf16 weights + scalars + per-(bin,block) histogram.
// bin = row>>7 (128-row bins, nBin<=512). Block b histograms its NE/64 slice
// via LDS atomics, writes ghist[bin*NSB+b].
// ---------------------------------------------------------------------------
__global__ __launch_bounds__(256) void k_prep(const float* __restrict__ W,
                                              const float* __restrict__ vw,
                                              const float* __restrict__ lg,
                                              const float* __restrict__ mg,
                                              const int* __restrict__ ei,
                                              short* __restrict__ WtF,
                                              short* __restrict__ vwF,
                                              float* __restrict__ sc,
                                              int* __restrict__ ghist,
                                              int ne, int nBin) {
    const int bid = blockIdx.x, tid = threadIdx.x;
    if (bid < 16) {                                // WtF: 4096 fragments
        int idx = bid * 256 + tid;                 // (kt,nf,lane)
        int kt = idx >> 9, rem = idx & 511;
        int nf = rem >> 6, lane = rem & 63;
        int l15 = lane & 15, lhi = lane >> 4;
        bf16x8 fr;
        #pragma unroll
        for (int i = 0; i < 8; ++i)
            fr[i] = f2b(W[(size_t)(kt*32 + lhi*8 + i) * EDIM + nf*16 + l15]);
        *(bf16x8*)(WtF + (size_t)idx * 8) = fr;
    } else if (bid < 24) {                         // vwF: 2048 fragments
        int idx = (bid - 16) * 256 + tid;          // (ks,nf,lane)
        int ks = idx >> 9, rem = idx & 511;
        int nf = rem >> 6, lane = rem & 63;
        int l15 = lane & 15, lhi = lane >> 4;
        bf16x8 fr;
        #pragma unroll
        for (int i = 0; i < 8; ++i)
            fr[i] = f2b(vw[(size_t)(nf*16 + l15) * EDIM + ks*32 + lhi*8 + i]);
        *(bf16x8*)(vwF + (size_t)idx * 8) = fr;
    } else if (bid == 24) {
        if (tid == 0) {
            const float a0 = -1e-9f, a1 = 1.0f + 1e-9f;
            float a_low = 0.f, b_low = 0.f, a_mid = 0.f, c_mid = 0.f;
            for (int i = 0; i < 5; ++i) {
                float l0 = fmaxf(lg[2*i], 0.f), l1 = fmaxf(lg[2*i+1], 0.f);
                a_low += l0 * a0 + l1 * a1;
                b_low += l0 * (1.f - a0) + l1 * (1.f - a1);
                float m0 = fmaxf(mg[2*i], 0.f), m1 = fmaxf(mg[2*i+1], 0.f);
                a_mid += m0 + m1;
                c_mid += m0 * a0 + m1 * a1;
            }
            sc[0] = a_low + a_mid;
            sc[1] = b_low - c_mid;
        }
    } else {                                       // hist blocks 25..25+NSB
        __shared__ int h[512];
        int b = bid - 25;
        h[tid] = 0; h[tid + 256] = 0;
        __syncthreads();
        const int per = (ne + NSB - 1) / NSB;
        const int lo = b * per, hi = min(lo + per, ne);
        for (int e = lo + tid; e < hi; e += 256)
            atomicAdd(&h[ei[e] >> 7], 1);          // LDS atomic only
        __syncthreads();
        for (int i = tid; i < nBin; i += 256)
            ghist[i * NSB + b] = h[i];
    }
}

// ---------------------------------------------------------------------------
// Mega dispatch, 512 threads:
//  blocks [0, NSB): radix SCATTER with SELF-COMPUTED bases (no k_scan
//    dispatch): bin totals + 512-wide Hillis-Steele scan in LDS + <=63-term
//    per-block partial, all from L2-resident ghist. Block 0 emits binStart[].
//    Scatter writes consecutive slots per (block,bin): no scattered-store
//    writeback tax, zero global atomics.
//  blocks [NSB, +gGemm): GEMM Y = relu(F@W)@vw^T (r19's proven config):
//    BM=128, 8 waves; all 96KB frag-major weights staged to LDS once
//    (lane-linear conflict-free reads, one barrier); all 16 F float4/lane
//    issued upfront (launch_bounds(512,2) -> 256-VGPR cap, no spill).
// ---------------------------------------------------------------------------
__global__ __launch_bounds__(512, 2) void k_mega(const float* __restrict__ F,
                                                 const short* __restrict__ WtF,
                                                 const short* __restrict__ vwF,
                                                 short* __restrict__ Yb,
                                                 const int* __restrict__ ei,
                                                 const float* __restrict__ ew,
                                                 const int* __restrict__ ghist,
                                                 int* __restrict__ binStart,
                                                 uint2* __restrict__ sorted,
                                                 int M, int ne, int nBin) {
    __shared__ short L[66560];       // 133120 B: WtL[0,32768) vwL[32768,49152) Sb[49152,66560)
    const int bid = blockIdx.x, tid = threadIdx.x;

    if (bid < NSB) {                 // ---- scatter path (自-scan + scatter) ----
        int* tot = (int*)L;                         // [512]
        int* pre = tot + 512;                       // [512]
        int* cur = pre + 512;                       // [512]
        const int b = bid;
        {                                           // bin totals
            int s = 0;
            if (tid < nBin)
                for (int bb = 0; bb < NSB; ++bb) s += ghist[tid * NSB + bb];
            tot[tid] = s;
            pre[tid] = s;
        }
        __syncthreads();
        for (int off = 1; off < 512; off <<= 1) {   // inclusive scan
            int x = (tid >= off) ? pre[tid - off] : 0;
            __syncthreads();
            pre[tid] += x;
            __syncthreads();
        }
        int excl = pre[tid] - tot[tid];             // exclusive bin base
        if (b == 0 && tid < nBin) binStart[tid] = excl;
        if (b == 0 && tid == 0)   binStart[nBin] = ne;
        if (tid < nBin) {                           // + partial over blocks < b
            int p = 0;
            for (int bb = 0; bb < b; ++bb) p += ghist[tid * NSB + bb];
            cur[tid] = excl + p;
        }
        __syncthreads();
        const int per = (ne + NSB - 1) / NSB;
        const int lo = b * per, hi = min(lo + per, ne);
        for (int e = lo + tid; e < hi; e += 512) {
            int r   = ei[e];
            int bin = r >> 7, rloc = r & 127;
            unsigned col = (unsigned)ei[ne + e];
            float    w   = ew[e];
            int pos = atomicAdd(&cur[bin], 1);      // LDS atomic only
            sorted[pos] = make_uint2(((unsigned)rloc << 16) | col,
                                     __float_as_uint(w));
        }
        return;
    }

    // ---- GEMM path (r19, unchanged) ----
    const int wave = tid >> 6, lane = tid & 63;
    const int l15  = lane & 15, lhi = lane >> 4;
    const int bm   = (bid - NSB) * 128;
    const int wrow = wave * 16;

    const int gr_a = bm + wrow + l15;
    const bool va  = gr_a < M;
    const float* fp = F + (size_t)(va ? gr_a : 0) * FIN + lhi * 8;
    float4 fa[16];
    #pragma unroll
    for (int t = 0; t < 16; ++t) {
        fa[t] = make_float4(0.f, 0.f, 0.f, 0.f);
        if (va) fa[t] = *(const float4*)(fp + (t >> 1) * 32 + (t & 1) * 4);
    }

    {   // stage ALL weights once (6144 int4, 12 per thread, coalesced from L2)
        const int4* s1 = (const int4*)WtF;
        int4* d1 = (int4*)L;
        #pragma unroll
        for (int i = 0; i < 8; ++i) d1[tid + i * 512] = s1[tid + i * 512];
        const int4* s2 = (const int4*)vwF;
        int4* d2 = (int4*)(L + 32768);
        #pragma unroll
        for (int i = 0; i < 4; ++i) d2[tid + i * 512] = s2[tid + i * 512];
    }
    __syncthreads();                 // the ONLY barrier

    f32x4 acc[8];
    #pragma unroll
    for (int b = 0; b < 8; ++b) acc[b] = (f32x4){0.f, 0.f, 0.f, 0.f};

    #pragma unroll
    for (int kt = 0; kt < 8; ++kt) {
        float4 a0 = fa[kt*2], a1 = fa[kt*2 + 1];
        bf16x8 af;
        af[0]=f2b(a0.x); af[1]=f2b(a0.y); af[2]=f2b(a0.z); af[3]=f2b(a0.w);
        af[4]=f2b(a1.x); af[5]=f2b(a1.y); af[6]=f2b(a1.z); af[7]=f2b(a1.w);
        #pragma unroll
        for (int nf = 0; nf < 8; ++nf) {
            bf16x8 bf = *(const bf16x8*)(&L[((kt*8 + nf)*64 + lane) * 8]);
            acc[nf] = __builtin_amdgcn_mfma_f32_16x16x32_bf16(af, bf, acc[nf], 0, 0, 0);
        }
    }

    short* Sb = L + 49152;
    #pragma unroll
    for (int nf = 0; nf < 8; ++nf)
        #pragma unroll
        for (int i = 0; i < 4; ++i)
            Sb[(wrow + lhi*4 + i) * 136 + nf*16 + l15] = f2b(fmaxf(acc[nf][i], 0.f));

    f32x4 acc2[8];
    #pragma unroll
    for (int b = 0; b < 8; ++b) acc2[b] = (f32x4){0.f, 0.f, 0.f, 0.f};

    #pragma unroll
    for (int ks = 0; ks < 4; ++ks) {
        bf16x8 af2 = *(const bf16x8*)(&Sb[(wrow + l15) * 136 + ks*32 + lhi*8]);
        #pragma unroll
        for (int nf = 0; nf < 8; ++nf) {
            bf16x8 bf2 = *(const bf16x8*)(&L[32768 + ((ks*8 + nf)*64 + lane) * 8]);
            acc2[nf] = __builtin_amdgcn_mfma_f32_16x16x32_bf16(af2, bf2, acc2[nf], 0, 0, 0);
        }
    }

    #pragma unroll
    for (int nf = 0; nf < 8; ++nf)
        #pragma unroll
        for (int i = 0; i < 4; ++i)
            Sb[(wrow + lhi*4 + i) * 136 + nf*16 + l15] = f2b(acc2[nf][i]);

    const int srow = lane >> 2;
    const int sch  = (lane & 3) * 32;
    const int gr_s = bm + wrow + srow;
    if (gr_s < M) {
        #pragma unroll
        for (int r = 0; r < 4; ++r) {
            float4 t = *(const float4*)(&Sb[(wrow + srow) * 136 + sch + r*8]);
            *(float4*)(Yb + (size_t)gr_s * EDIM + sch + r*8) = t;
        }
    }
}

// ---------------------------------------------------------------------------
// Gather3: block = one 128-row bin. Direct LDS fp32 accumulation — NO CSR
// build, no per-row serial walk, no caps (exact). acc uses even/odd split
// layout so ds_add_f32 is stride-4B (conflict-free). Streams the bin's
// CONTIGUOUS sorted slice 8-edges-deep per wave (independent Y loads);
// coalesced epilogue with Bb*Y + 2*vb fused.
// ---------------------------------------------------------------------------
__global__ __launch_bounds__(1024) void k_gather3(const uint2* __restrict__ sorted,
                                                  const int* __restrict__ binStart,
                                                  const __hip_bfloat162* __restrict__ Yb,
                                                  const float* __restrict__ vb,
                                                  const float* __restrict__ sc,
                                                  float* __restrict__ out, int M) {
    __shared__ float acc[RB * EDIM];   // 64KB: [r][0..63]=even floats, [r][64..127]=odd
    const int tid = threadIdx.x, wave = tid >> 6, lane = tid & 63;
    const int bin = blockIdx.x;
    const int n0 = __builtin_amdgcn_readfirstlane(binStart[bin]);
    const int n1 = __builtin_amdgcn_readfirstlane(binStart[bin + 1]);

    for (int i = tid; i < RB * EDIM; i += 1024) acc[i] = 0.f;
    __syncthreads();

    for (int i0 = n0 + wave * 8; i0 < n1; i0 += 16 * 8) {
        uint2 ent[8]; float2 y[8]; bool m[8];
        #pragma unroll
        for (int u = 0; u < 8; ++u) {
            int i = i0 + u;
            m[u] = i < n1;
            ent[u] = m[u] ? sorted[i] : make_uint2(0, 0);
        }
        #pragma unroll
        for (int u = 0; u < 8; ++u) {
            int col = ent[u].x & 0xFFFF;
            y[u] = __bfloat1622float2(Yb[(size_t)col * 64 + lane]);
        }
        #pragma unroll
        for (int u = 0; u < 8; ++u) {
            if (m[u]) {
                float w  = __uint_as_float(ent[u].y);
                int rloc = ent[u].x >> 16;
                atomicAdd(&acc[rloc * EDIM + lane],      w * y[u].x);
                atomicAdd(&acc[rloc * EDIM + 64 + lane], w * y[u].y);
            }
        }
    }
    __syncthreads();

    const float Aa = sc[0], Bb = sc[1];
    float2 bb = *(const float2*)(vb + lane * 2);
    #pragma unroll
    for (int s = 0; s < 8; ++s) {                  // 16 waves x 8 rows
        int lr  = wave * 8 + s;
        int row = bin * RB + lr;
        if (row >= M) break;
        float2 y = __bfloat1622float2(Yb[(size_t)row * 64 + lane]);
        float2 o;
        o.x = fmaf(Aa, acc[lr * EDIM + lane],      fmaf(Bb, y.x, 2.f * bb.x));
        o.y = fmaf(Aa, acc[lr * EDIM + 64 + lane], fmaf(Bb, y.y, 2.f * bb.y));
        *(float2*)(out + (size_t)row * EDIM + lane * 2) = o;
    }
}

// ---------------------------------------------------------------------------
extern "C" void kernel_launch(void* const* d_in, const int* in_sizes, int n_in,
                              void* d_out, int out_size, void* d_ws, size_t ws_size,
                              hipStream_t stream) {
    const float* feature = (const float*)d_in[0];
    const int*   eidx    = (const int*)d_in[1];   // [2, NE] int32
    const float* ew      = (const float*)d_in[2];
    const float* weight  = (const float*)d_in[3];
    const float* lg      = (const float*)d_in[4];
    const float* mg      = (const float*)d_in[5];
    // d_in[6..9] = q_w,q_b,k_w,k_b provably unused: softmax over the query axis
    // followed by sum over the query axis makes each k-column of w sum to 1.
    const float* vw      = (const float*)d_in[10];
    const float* vb      = (const float*)d_in[11];
    float* out = (float*)d_out;

    const int M  = in_sizes[0] / FIN;   // 50000 (col fits u16; nBin <= 512)
    const int NE = in_sizes[2];         // 600000

    const int nBin = (M + RB - 1) / RB;            // 391 bins of 128 rows

    // workspace layout (~17.9 MB)
    char* ws = (char*)d_ws;
    short* Yb      = (short*)ws;                                   // 12.8 MB
    char* p = ws + (size_t)M * EDIM * 2;
    uint2* sorted  = (uint2*)p;      p += (size_t)NE * 8;          // 4.8 MB
    int*   ghist   = (int*)p;        p += (size_t)nBin * NSB * 4;  // 100 KB
    int*   binStart= (int*)p;        p += (size_t)(nBin + 1) * 4;
    p = (char*)(((size_t)p + 15) & ~(size_t)15);
    short* WtF     = (short*)p;      p += (size_t)EDIM * FIN * 2;  // 64 KB
    short* vwF     = (short*)p;      p += (size_t)EDIM * EDIM * 2; // 32 KB
    float* sc      = (float*)p;

    k_prep<<<25 + NSB, 256, 0, stream>>>(weight, vw, lg, mg, eidx,
                                         WtF, vwF, sc, ghist, NE, nBin);

    const int gGemm = (M + 127) / 128;             // 391 (BM=128)
    k_mega<<<NSB + gGemm, 512, 0, stream>>>(feature, WtF, vwF, Yb,
                                            eidx, ew, ghist, binStart, sorted,
                                            M, NE, nBin);

    k_gather3<<<nBin, 1024, 0, stream>>>(sorted, binStart,
                                         (const __hip_bfloat162*)Yb,
                                         vb, sc, out, M);
}